// Round 6
// baseline (4888.258 us; speedup 1.0000x reference)
//
#include <hip/hip_runtime.h>

// Sizes
#define BB 64
#define LL 25
#define DD 128
#define BL 1600           // B*L
#define POI_N 10000
#define CAT_N 400
#define NBLK 64           // persistent kernel: one block per batch element
#define NTHR 1024         // R6: 16 waves/block = 4 waves/SIMD
#define NSH 8             // arrival shards for the mv-sync counter

// ---------------------------------------------------------------------------
// mv-sync: the ONLY cross-block sync in the chain. No fences anywhere:
// mv data travels via cache-bypassing agent-scope atomic stores/loads, so
// L1/L2 are never invalidated (R1-R3 lesson: acquire fences cost ~14us each).
// Arrival counter sharded 8 ways (R2 lesson: single-line RMWs serialize).
// ---------------------------------------------------------------------------
__device__ __forceinline__ void mvsync(unsigned* __restrict__ cnt, int ci, int bx)
{
    __syncthreads();
    if (threadIdx.x == 0) {
        unsigned* base = cnt + ci * (NSH * 32);
        __hip_atomic_fetch_add(base + (bx & (NSH - 1)) * 32, 1u,
                               __ATOMIC_RELEASE, __HIP_MEMORY_SCOPE_AGENT);
        for (;;) {
            unsigned s = 0;
#pragma unroll
            for (int g = 0; g < NSH; g++)
                s += __hip_atomic_load(base + g * 32, __ATOMIC_RELAXED,
                                       __HIP_MEMORY_SCOPE_AGENT);
            if (s >= NBLK) break;
            __builtin_amdgcn_s_sleep(1);
        }
    }
    __syncthreads();
}

// ---------------------------------------------------------------------------
// Distance min/max, stage 1: per-row block reduce, PLAIN stores.
// ---------------------------------------------------------------------------
__global__ __launch_bounds__(256) void minmax1_kernel(
    const int* __restrict__ poi, const float* __restrict__ Dm,
    float* __restrict__ mxA, float* __restrict__ mnA)
{
    int bl = blockIdx.x;
    const float4* r = (const float4*)(Dm + (size_t)poi[bl] * POI_N);
    float mx = -1e30f, mn = 1e30f;
    for (int i = threadIdx.x; i < POI_N / 4; i += 256) {
        float4 v4 = r[i];
        mx = fmaxf(mx, fmaxf(fmaxf(v4.x, v4.y), fmaxf(v4.z, v4.w)));
        mn = fminf(mn, fminf(fminf(v4.x, v4.y), fminf(v4.z, v4.w)));
    }
    for (int off = 32; off > 0; off >>= 1) {
        mx = fmaxf(mx, __shfl_down(mx, off));
        mn = fminf(mn, __shfl_down(mn, off));
    }
    __shared__ float smx[4], smn[4];
    int lid = threadIdx.x & 63, wid = threadIdx.x >> 6;
    if (lid == 0) { smx[wid] = mx; smn[wid] = mn; }
    __syncthreads();
    if (threadIdx.x == 0) {
        mxA[bl] = fmaxf(fmaxf(smx[0], smx[1]), fmaxf(smx[2], smx[3]));
        mnA[bl] = fminf(fminf(smn[0], smn[1]), fminf(smn[2], smn[3]));
    }
}

// Stage 2: one block reduces the 1600 pairs; plain stores of gmax/gmin.
__global__ __launch_bounds__(256) void minmax2_kernel(
    const float* __restrict__ mxA, const float* __restrict__ mnA, float* __restrict__ mmf)
{
    float mx = -1e30f, mn = 1e30f;
    for (int i = threadIdx.x; i < BL; i += 256) {
        mx = fmaxf(mx, mxA[i]);
        mn = fminf(mn, mnA[i]);
    }
    for (int off = 32; off > 0; off >>= 1) {
        mx = fmaxf(mx, __shfl_down(mx, off));
        mn = fminf(mn, __shfl_down(mn, off));
    }
    __shared__ float smx[4], smn[4];
    int lid = threadIdx.x & 63, wid = threadIdx.x >> 6;
    if (lid == 0) { smx[wid] = mx; smn[wid] = mn; }
    __syncthreads();
    if (threadIdx.x == 0) {
        mmf[0] = fmaxf(fmaxf(smx[0], smx[1]), fmaxf(smx[2], smx[3]));
        mmf[1] = fminf(fminf(smn[0], smn[1]), fminf(smn[2], smn[3]));
    }
}

// ---------------------------------------------------------------------------
// Persistent per-b ac-chain, 1024 threads (16 waves, 4/SIMD).
// R6 GEMM: col n=t&127, rowgroup rg=t>>7 -> rows {rg,rg+8,rg+16,(24 if rg==0)}.
// W row streamed DIRECTLY from global into regs (no LDS staging, no internal
// barriers; W lines are L2-hot -- all 64 blocks read the same W). A-operand
// LDS reads are wave-uniform broadcasts. Q,K results stay in LDS (sQ,sK) --
// no global round-trip; V and out-proj go to global (needed later).
// ---------------------------------------------------------------------------
__global__ __launch_bounds__(NTHR) void persist_kernel(
    const int* __restrict__ user, const int* __restrict__ poi, const int* __restrict__ cat,
    const int* __restrict__ tod, const int* __restrict__ dow,
    const float* __restrict__ ue, const float* __restrict__ pe, const float* __restrict__ ce,
    const float* __restrict__ te, const float* __restrict__ de,
    const float* __restrict__ uec, const float* __restrict__ tec, const float* __restrict__ dec,
    const float* __restrict__ W, const float* __restrict__ Bv,
    const float* __restrict__ vw, const float* __restrict__ vbp,
    float* __restrict__ O0, float* __restrict__ C0, float* __restrict__ O1, float* __restrict__ C1,
    float* __restrict__ Vg,
    unsigned* __restrict__ MVu,          // 8 x 1600 floats as uints (coherent mailbox)
    unsigned* __restrict__ cnt,
    float* __restrict__ out_cat)
{
    __shared__ float sA[LL][132];      // x / agg
    __shared__ float sB[LL][132];      // xk
    __shared__ float sQ[LL][132];      // Q (never leaves the block)
    __shared__ float sK[LL][132];      // K (never leaves the block)
    __shared__ float crb[LL][16];
    __shared__ float smv[LL];
    __shared__ float pbm[8][LL];
    __shared__ float sbm[LL];
    __shared__ int   sidx[3];
    __shared__ float sw3[3];
    __shared__ float yv[DD];
    __shared__ float svw[LL];

    int bx = blockIdx.x, t = threadIdx.x;
    int b = bx;
    int n = t & 127, rg = t >> 7;      // rg is wave-uniform (wave w -> rg = w>>1)

    auto dot16 = [](float4 w0, float4 w1, float4 w2, float4 w3, const float* a) -> float {
        float4 a0 = *(const float4*)a, a1 = *(const float4*)(a + 4);
        float4 a2 = *(const float4*)(a + 8), a3 = *(const float4*)(a + 12);
        return w0.x*a0.x + w0.y*a0.y + w0.z*a0.z + w0.w*a0.w
             + w1.x*a1.x + w1.y*a1.y + w1.z*a1.z + w1.w*a1.w
             + w2.x*a2.x + w2.y*a2.y + w2.z*a2.z + w2.w*a2.w
             + w3.x*a3.x + w3.y*a3.y + w3.z*a3.z + w3.w*a3.w;
    };

    // out[25][128] = A @ Wm^T + bias.  Ld!=nullptr -> LDS dest, else global Gd.
    auto gemmL = [&](const float (&A)[LL][132], const float* Wm, const float* bias,
                     float (*Ld)[132], float* Gd) {
        float acc0 = 0.f, acc1 = 0.f, acc2 = 0.f, acc3 = 0.f;
        const float* wrow = Wm + n * DD;
#pragma unroll
        for (int kb = 0; kb < 128; kb += 16) {
            float4 w0 = *(const float4*)(wrow + kb);
            float4 w1 = *(const float4*)(wrow + kb + 4);
            float4 w2 = *(const float4*)(wrow + kb + 8);
            float4 w3 = *(const float4*)(wrow + kb + 12);
            acc0 += dot16(w0, w1, w2, w3, &A[rg][kb]);
            acc1 += dot16(w0, w1, w2, w3, &A[rg + 8][kb]);
            acc2 += dot16(w0, w1, w2, w3, &A[rg + 16][kb]);
            if (rg == 0) acc3 += dot16(w0, w1, w2, w3, &A[24][kb]);
        }
        float bvv = bias[n];
        if (Ld) {
            Ld[rg][n]      = acc0 + bvv;
            Ld[rg + 8][n]  = acc1 + bvv;
            Ld[rg + 16][n] = acc2 + bvv;
            if (rg == 0) Ld[24][n] = acc3 + bvv;
        } else {
            Gd[rg * DD + n]        = acc0 + bvv;
            Gd[(rg + 8) * DD + n]  = acc1 + bvv;
            Gd[(rg + 16) * DD + n] = acc2 + bvv;
            if (rg == 0) Gd[24 * DD + n] = acc3 + bvv;
        }
    };

    // ================= embed: own 25 rows ==================================
    if (t < 800) {
        int l = t >> 5, c = (t & 31) << 2;
        int bl = b * LL + l;
        int u = user[bl], p = poi[bl], cc = cat[bl], td = tod[bl], dw = dow[bl];
        float4 a0 = *(const float4*)(ue + u * DD + c);
        float4 a1 = *(const float4*)(pe + p * DD + c);
        float4 a2 = *(const float4*)(te + td * DD + c);
        float4 a3 = *(const float4*)(de + dw * DD + c);
        float4 x;
        x.x = a0.x + a1.x + a2.x + a3.x; x.y = a0.y + a1.y + a2.y + a3.y;
        x.z = a0.z + a1.z + a2.z + a3.z; x.w = a0.w + a1.w + a2.w + a3.w;
        *(float4*)(O0 + bl * DD + c) = x;
        float4 b0 = *(const float4*)(uec + u * DD + c);
        float4 b1 = *(const float4*)(ce + cc * DD + c);
        float4 b2 = *(const float4*)(tec + td * DD + c);
        float4 b3 = *(const float4*)(dec + dw * DD + c);
        float4 xc;
        xc.x = b0.x + b1.x + b2.x + b3.x; xc.y = b0.y + b1.y + b2.y + b3.y;
        xc.z = b0.z + b1.z + b2.z + b3.z; xc.w = b0.w + b1.w + b2.w + b3.w;
        *(float4*)(C0 + bl * DD + c) = xc;
    }
    __syncthreads();

    // ================= 8 autocorrelation-attention calls ===================
    float* bufs[4] = {O0, C0, O1, C1};
    const int qsel[8] = {0, 1, 2, 3, 0, 1, 2, 3};
    const int ksel[8] = {0, 1, 3, 0, 0, 1, 3, 0};
    const int dsel[8] = {2, 3, 0, 1, 2, 3, 0, 1};

    float* Vb = Vg + b * LL * DD;

#pragma unroll 1
    for (int ci = 0; ci < 8; ++ci) {
        const float* qx  = bufs[qsel[ci]] + b * LL * DD;
        const float* kx  = bufs[ksel[ci]] + b * LL * DD;   // kx == vx
        float*       dst = bufs[dsel[ci]] + b * LL * DD;
        const float* Wb  = W  + (size_t)ci * 4 * DD * DD;
        const float* Bb  = Bv + (size_t)ci * 4 * DD;

        // ---- stage src rows (own writes from last call: L2-hot)
        if (t < 800) {
            int l = t >> 5, c = (t & 31) << 2;
            *(float4*)&sA[l][c] = *(const float4*)(qx + l * DD + c);
            *(float4*)&sB[l][c] = *(const float4*)(kx + l * DD + c);
        }
        __syncthreads();

        // ---- proj q/k/v: zero internal barriers; W streamed from L2
        gemmL(sA, Wb,               Bb,          sQ, nullptr);
        gemmL(sB, Wb + 1 * DD * DD, Bb + DD,     sK, nullptr);
        gemmL(sB, Wb + 2 * DD * DD, Bb + 2 * DD, nullptr, Vb);
        __syncthreads();

        // ---- corr: mv[tau] = (1/128) sum_s Q[(s+tau)%25,:] . K[s,:]
        {
            int wid = t >> 6;
            int srow = t >> 5, dc = (t & 31) << 2;   // valid when t < 800
            for (int tau = 0; tau < LL; tau++) {
                float s = 0.f;
                if (t < 800) {
                    int qrow = srow + tau; if (qrow >= LL) qrow -= LL;
                    float4 a = *(const float4*)&sQ[qrow][dc];
                    float4 g = *(const float4*)&sK[srow][dc];
                    s = a.x * g.x + a.y * g.y + a.z * g.z + a.w * g.w;
                }
                for (int off = 32; off > 0; off >>= 1) s += __shfl_down(s, off);
                if ((t & 63) == 0) crb[tau][wid] = s;
            }
        }
        __syncthreads();
        if (t < LL) {
            float v = 0.f;
#pragma unroll
            for (int w2 = 0; w2 < 16; w2++) v += crb[t][w2];
            v *= (1.0f / 128.0f);
            smv[t] = v;
            __hip_atomic_store(&MVu[ci * BL + b * LL + t], __float_as_uint(v),
                               __ATOMIC_RELAXED, __HIP_MEMORY_SCOPE_AGENT);
        }

        // ---- the one cross-block sync per call
        mvsync(cnt, ci, bx);

        // ---- batch-mean over b (coherent loads), redundant per block
        if (t < 200) {
            int g = t / LL, tau = t - g * LL;
            float s = 0.f;
#pragma unroll
            for (int k2 = 0; k2 < 8; k2++) {
                int b2 = g * 8 + k2;
                s += __uint_as_float(__hip_atomic_load(&MVu[ci * BL + b2 * LL + tau],
                                                       __ATOMIC_RELAXED,
                                                       __HIP_MEMORY_SCOPE_AGENT));
            }
            pbm[g][tau] = s;
        }
        __syncthreads();
        if (t < LL) {
            float s = 0.f;
#pragma unroll
            for (int g = 0; g < 8; g++) s += pbm[g][t];
            sbm[t] = s;
        }
        __syncthreads();
        if (t == 0) {
            float loc[LL];
            for (int i = 0; i < LL; i++) loc[i] = sbm[i];
            for (int j = 0; j < 3; j++) {
                int bi = 0; float bvv = loc[0];
                for (int i = 1; i < LL; i++) if (loc[i] > bvv) { bvv = loc[i]; bi = i; }
                sidx[j] = bi; loc[bi] = -1e30f;
            }
            float w0 = smv[sidx[0]], w1 = smv[sidx[1]], w2 = smv[sidx[2]];
            float m = fmaxf(w0, fmaxf(w1, w2));
            float e0 = expf(w0 - m), e1 = expf(w1 - m), e2 = expf(w2 - m);
            float inv = 1.0f / (e0 + e1 + e2);
            sw3[0] = e0 * inv; sw3[1] = e1 * inv; sw3[2] = e2 * inv;
        }
        __syncthreads();

        // ---- agg into sA (V rows: own-block global writes, L2-hot)
        if (t < 800) {
            int l = t >> 5, c = (t & 31) << 2;
            int i0 = sidx[0], i1 = sidx[1], i2x = sidx[2];
            float w0 = sw3[0], w1 = sw3[1], w2 = sw3[2];
            int l0 = l + i0;  if (l0 >= LL) l0 -= LL;
            int l1 = l + i1;  if (l1 >= LL) l1 -= LL;
            int l2 = l + i2x; if (l2 >= LL) l2 -= LL;
            float4 v0 = *(const float4*)(Vb + l0 * DD + c);
            float4 v1 = *(const float4*)(Vb + l1 * DD + c);
            float4 v2 = *(const float4*)(Vb + l2 * DD + c);
            float4 a;
            a.x = w0 * v0.x + w1 * v1.x + w2 * v2.x;
            a.y = w0 * v0.y + w1 * v1.y + w2 * v2.y;
            a.z = w0 * v0.z + w1 * v1.z + w2 * v2.z;
            a.w = w0 * v0.w + w1 * v1.w + w2 * v2.w;
            *(float4*)&sA[l][c] = a;
        }
        __syncthreads();

        // ---- out-proj: dst = agg @ W3^T + b3
        gemmL(sA, Wb + 3 * DD * DD, Bb + 3 * DD, nullptr, dst);
        __syncthreads();
    }

    // ================= precat: own b =======================================
    {
        if (t < LL) svw[t] = vw[t];
        __syncthreads();
        if (t < DD) {
            float s = 0.f;
            for (int l = 0; l < LL; l++) s += svw[l] * C0[(b * LL + l) * DD + t];
            yv[t] = s;
        }
        __syncthreads();
        float vb = vbp[0];
        for (int c = t; c < CAT_N; c += NTHR) {
            float s = 0.f;
            for (int d = 0; d < DD; d += 4) {
                float4 ce4 = *(const float4*)(ce + c * DD + d);
                s += ce4.x * yv[d] + ce4.y * yv[d + 1] + ce4.z * yv[d + 2] + ce4.w * yv[d + 3];
            }
            out_cat[b * CAT_N + c] = s + vb;
        }
    }
}

// ---------------------------------------------------------------------------
// pre_poi[b,p] = vb + sum_l vw[l] * exp(-D[poi[b,l],p]/(gmax-gmin))
//                                 * (poi_emb[p] . out[b,l,:])
// R6: sS overlaid on sPc (sS only live after sPc's last read; written after
// the final kb barrier). LDS 61KB -> 48.5KB => 3 blocks/CU (was 1) => 3
// waves/SIMD during the latency-bound phases.
// ---------------------------------------------------------------------------
__global__ __launch_bounds__(256, 3) void prepoi_kernel(
    const float* __restrict__ outp, const float* __restrict__ poi_emb,
    const int* __restrict__ poi_idx, const float* __restrict__ Dm,
    const float* __restrict__ mmf, const float* __restrict__ vw,
    const float* __restrict__ vbp, float* __restrict__ dstp)
{
    int b = blockIdx.y;
    int pbase = blockIdx.x << 7;
    __shared__ float sO[LL][132];
    __shared__ __align__(16) char ovl[128 * 68 * 4];                 // sPc / sS overlay
    float (*sPc)[68]  = reinterpret_cast<float(*)[68]>(ovl);
    float (*sS)[132]  = reinterpret_cast<float(*)[132]>(ovl);
    __shared__ float svw[LL];
    __shared__ int srow[LL];
    __shared__ float red[128];
    int t = threadIdx.x;

    for (int i = t; i < 800; i += 256) {
        int l = i >> 5, c = (i & 31) << 2;
        *(float4*)&sO[l][c] = *(const float4*)(outp + (b * LL + l) * DD + c);
    }
    if (t < LL) { svw[t] = vw[t]; srow[t] = poi_idx[b * LL + t]; }
    __syncthreads();

    int nh = t & 31, mg = t >> 5;
    float acc[4][4] = {};
    for (int kb = 0; kb < 128; kb += 64) {
        for (int i = t; i < 128 * 16; i += 256) {
            int p = i >> 4, c = (i & 15) << 2;
            float4 val = {0.f, 0.f, 0.f, 0.f};
            if (pbase + p < POI_N) val = *(const float4*)(poi_emb + (pbase + p) * DD + kb + c);
            *(float4*)&sPc[p][c] = val;
        }
        __syncthreads();
#pragma unroll 4
        for (int kk = 0; kk < 64; kk += 4) {
            float4 a0 = *(const float4*)&sO[mg][kb + kk];
            float4 a1 = *(const float4*)&sO[mg + 8][kb + kk];
            float4 a2 = *(const float4*)&sO[mg + 16][kb + kk];
            float4 a3 = {0.f, 0.f, 0.f, 0.f};
            if (mg == 0) a3 = *(const float4*)&sO[24][kb + kk];
#pragma unroll
            for (int j = 0; j < 4; j++) {
                float4 p4 = *(const float4*)&sPc[nh + 32 * j][kk];
                acc[j][0] += p4.x * a0.x + p4.y * a0.y + p4.z * a0.z + p4.w * a0.w;
                acc[j][1] += p4.x * a1.x + p4.y * a1.y + p4.z * a1.z + p4.w * a1.w;
                acc[j][2] += p4.x * a2.x + p4.y * a2.y + p4.z * a2.z + p4.w * a2.w;
                acc[j][3] += p4.x * a3.x + p4.y * a3.y + p4.z * a3.z + p4.w * a3.w;
            }
        }
        __syncthreads();   // also protects the overlay: all sPc reads done
    }
#pragma unroll
    for (int j = 0; j < 4; j++) {
        int pl = nh + 32 * j;
        sS[mg][pl]      = acc[j][0];
        sS[mg + 8][pl]  = acc[j][1];
        sS[mg + 16][pl] = acc[j][2];
        if (mg == 0) sS[24][pl] = acc[j][3];
    }
    __syncthreads();

    float gmax = mmf[0];
    float gmin = mmf[1];
    float ninv = -1.0f / (gmax - gmin);
    int pp = t & 127, half = t >> 7;
    int p = pbase + pp;
    float s = 0.f;
    if (p < POI_N) {
        int l0 = half ? 13 : 0, l1 = half ? 25 : 13;
        for (int l = l0; l < l1; l++) {
            float dv = Dm[(size_t)srow[l] * POI_N + p];
            s += svw[l] * expf(dv * ninv) * sS[l][pp];
        }
    }
    if (half) red[pp] = s;
    __syncthreads();
    if (!half && p < POI_N)
        dstp[(size_t)b * POI_N + p] = s + red[pp] + vbp[0];
}

// ---------------------------------------------------------------------------
extern "C" void kernel_launch(void* const* d_in, const int* in_sizes, int n_in,
                              void* d_out, int out_size, void* d_ws, size_t ws_size,
                              hipStream_t stream)
{
    const int*   user = (const int*)d_in[0];
    const int*   poi  = (const int*)d_in[1];
    const int*   cat  = (const int*)d_in[2];
    const int*   tod  = (const int*)d_in[5];
    const int*   dow  = (const int*)d_in[6];
    const float* ue   = (const float*)d_in[8];
    const float* pe   = (const float*)d_in[9];
    const float* ce   = (const float*)d_in[10];
    const float* te   = (const float*)d_in[11];
    const float* de   = (const float*)d_in[12];
    const float* uec  = (const float*)d_in[13];
    const float* tec  = (const float*)d_in[14];
    const float* dec  = (const float*)d_in[15];
    const float* W    = (const float*)d_in[16];
    const float* Bv   = (const float*)d_in[17];
    const float* vw   = (const float*)d_in[18];
    const float* vb   = (const float*)d_in[19];
    const float* Dm   = (const float*)d_in[20];

    float* ws = (float*)d_ws;
    float* O0 = ws;
    float* C0 = ws + 204800;
    float* O1 = ws + 409600;
    float* C1 = ws + 614400;
    float* Vg = ws + 1228800;
    unsigned* MVu = (unsigned*)(ws + 1433600);     // 8 calls x 1600 mv mailbox
    float* mxA = ws + 1446400;                     // 1600
    float* mnA = ws + 1448000;                     // 1600
    unsigned* CNT = (unsigned*)(ws + 1449600);     // 8 calls x 8 shards x 32
    float* MMF = ws + 1449600 + 2048;              // gmax, gmin

    float* out_poi = (float*)d_out;
    float* out_cat = out_poi + BB * POI_N;

    // zero the sync counters only
    hipMemsetAsync(CNT, 0, 8 * NSH * 32 * sizeof(unsigned), stream);

    minmax1_kernel<<<BL, 256, 0, stream>>>(poi, Dm, mxA, mnA);
    minmax2_kernel<<<1, 256, 0, stream>>>(mxA, mnA, MMF);

    persist_kernel<<<NBLK, NTHR, 0, stream>>>(
        user, poi, cat, tod, dow, ue, pe, ce, te, de, uec, tec, dec,
        W, Bv, vw, vb, O0, C0, O1, C1, Vg, MVu, CNT, out_cat);

    prepoi_kernel<<<dim3(79, BB), 256, 0, stream>>>(O0, pe, poi, Dm, MMF, vw, vb, out_poi);
}

// Round 7
// 1080.328 us; speedup vs baseline: 4.5248x; 4.5248x over previous
//
#include <hip/hip_runtime.h>

// Sizes
#define BB 64
#define LL 25
#define DD 128
#define BL 1600           // B*L
#define POI_N 10000
#define CAT_N 400
#define NBLK 64           // persistent kernel: one block per batch element
#define NTHR 512          // 8 waves/block = 2 waves/SIMD (R5 proven: 454us)
#define NSH 8             // arrival shards for the mv-sync counter

// ---------------------------------------------------------------------------
// mv-sync: the ONLY cross-block sync in the chain. No fences anywhere:
// mv data travels via cache-bypassing agent-scope atomic stores/loads, so
// L1/L2 are never invalidated (R1-R3 lesson: acquire fences cost ~14us each).
// Arrival counter sharded 8 ways (R2 lesson: single-line RMWs serialize).
// R6 lesson (logged): never stream B-operand rows per-output-column from
// global (512B lane stride = 64 lines/wave + 8x redundancy = 4GB traffic).
// ---------------------------------------------------------------------------
__device__ __forceinline__ void mvsync(unsigned* __restrict__ cnt, int ci, int bx)
{
    __syncthreads();
    if (threadIdx.x == 0) {
        unsigned* base = cnt + ci * (NSH * 32);
        __hip_atomic_fetch_add(base + (bx & (NSH - 1)) * 32, 1u,
                               __ATOMIC_RELEASE, __HIP_MEMORY_SCOPE_AGENT);
        for (;;) {
            unsigned s = 0;
#pragma unroll
            for (int g = 0; g < NSH; g++)
                s += __hip_atomic_load(base + g * 32, __ATOMIC_RELAXED,
                                       __HIP_MEMORY_SCOPE_AGENT);
            if (s >= NBLK) break;
            __builtin_amdgcn_s_sleep(1);
        }
    }
    __syncthreads();
}

// ---------------------------------------------------------------------------
// Distance min/max, stage 1: per-row block reduce, PLAIN stores.
// ---------------------------------------------------------------------------
__global__ __launch_bounds__(256) void minmax1_kernel(
    const int* __restrict__ poi, const float* __restrict__ Dm,
    float* __restrict__ mxA, float* __restrict__ mnA)
{
    int bl = blockIdx.x;
    const float4* r = (const float4*)(Dm + (size_t)poi[bl] * POI_N);
    float mx = -1e30f, mn = 1e30f;
    for (int i = threadIdx.x; i < POI_N / 4; i += 256) {
        float4 v4 = r[i];
        mx = fmaxf(mx, fmaxf(fmaxf(v4.x, v4.y), fmaxf(v4.z, v4.w)));
        mn = fminf(mn, fminf(fminf(v4.x, v4.y), fminf(v4.z, v4.w)));
    }
    for (int off = 32; off > 0; off >>= 1) {
        mx = fmaxf(mx, __shfl_down(mx, off));
        mn = fminf(mn, __shfl_down(mn, off));
    }
    __shared__ float smx[4], smn[4];
    int lid = threadIdx.x & 63, wid = threadIdx.x >> 6;
    if (lid == 0) { smx[wid] = mx; smn[wid] = mn; }
    __syncthreads();
    if (threadIdx.x == 0) {
        mxA[bl] = fmaxf(fmaxf(smx[0], smx[1]), fmaxf(smx[2], smx[3]));
        mnA[bl] = fminf(fminf(smn[0], smn[1]), fminf(smn[2], smn[3]));
    }
}

// Stage 2: one block reduces the 1600 pairs; plain stores of gmax/gmin.
__global__ __launch_bounds__(256) void minmax2_kernel(
    const float* __restrict__ mxA, const float* __restrict__ mnA, float* __restrict__ mmf)
{
    float mx = -1e30f, mn = 1e30f;
    for (int i = threadIdx.x; i < BL; i += 256) {
        mx = fmaxf(mx, mxA[i]);
        mn = fminf(mn, mnA[i]);
    }
    for (int off = 32; off > 0; off >>= 1) {
        mx = fmaxf(mx, __shfl_down(mx, off));
        mn = fminf(mn, __shfl_down(mn, off));
    }
    __shared__ float smx[4], smn[4];
    int lid = threadIdx.x & 63, wid = threadIdx.x >> 6;
    if (lid == 0) { smx[wid] = mx; smn[wid] = mn; }
    __syncthreads();
    if (threadIdx.x == 0) {
        mmf[0] = fmaxf(fmaxf(smx[0], smx[1]), fmaxf(smx[2], smx[3]));
        mmf[1] = fminf(fminf(smn[0], smn[1]), fminf(smn[2], smn[3]));
    }
}

// ---------------------------------------------------------------------------
// Persistent per-b ac-chain, 512 threads (8 waves) -- exact R5 structure
// (proven 454us). GEMM thread map: nh2=t&63 -> cols {nh2,nh2+64};
// mg2=t>>6 (wave id) -> rows {mg2,mg2+8,mg2+16,(24 if mg2==0)}.
// W staged through LDS in 64-wide K chunks (coalesced global reads).
// ---------------------------------------------------------------------------
__global__ __launch_bounds__(NTHR) void persist_kernel(
    const int* __restrict__ user, const int* __restrict__ poi, const int* __restrict__ cat,
    const int* __restrict__ tod, const int* __restrict__ dow,
    const float* __restrict__ ue, const float* __restrict__ pe, const float* __restrict__ ce,
    const float* __restrict__ te, const float* __restrict__ de,
    const float* __restrict__ uec, const float* __restrict__ tec, const float* __restrict__ dec,
    const float* __restrict__ W, const float* __restrict__ Bv,
    const float* __restrict__ vw, const float* __restrict__ vbp,
    float* __restrict__ O0, float* __restrict__ C0, float* __restrict__ O1, float* __restrict__ C1,
    float* __restrict__ Qg, float* __restrict__ Kg, float* __restrict__ Vg,
    unsigned* __restrict__ MVu,          // 8 x 1600 floats as uints (coherent mailbox)
    unsigned* __restrict__ cnt,
    float* __restrict__ out_cat)
{
    __shared__ float sA[LL][132];     // A-tile / q-src / Q / agg
    __shared__ float sB[LL][132];     // k-src / K
    __shared__ float sWc[128][68];    // W K-chunk staging
    __shared__ float crb[LL][8];
    __shared__ float smv[LL];         // own b's mv row
    __shared__ float pbm[8][LL];      // batch-mean partials
    __shared__ float sbm[LL];
    __shared__ int   sidx[3];
    __shared__ float sw3[3];
    __shared__ float yv[DD];
    __shared__ float svw[LL];

    int bx = blockIdx.x, t = threadIdx.x;
    int b = bx;
    int nh2 = t & 63, mg2 = t >> 6;

    // ---- GEMM: out[25][128] = A[25][128] @ Wm[128][128]^T + bias -> gdst
    auto gemm = [&](const float (&A)[LL][132], const float* Wm,
                    const float* bias, float* gdst) {
        float acc[2][4] = {};
        for (int kb = 0; kb < 128; kb += 64) {
            for (int i = t; i < 128 * 16; i += NTHR) {
                int n = i >> 4, c = (i & 15) << 2;
                *(float4*)&sWc[n][c] = *(const float4*)(Wm + n * DD + kb + c);
            }
            __syncthreads();
#pragma unroll 4
            for (int kk = 0; kk < 64; kk += 4) {
                float4 a0 = *(const float4*)&A[mg2][kb + kk];
                float4 a1 = *(const float4*)&A[mg2 + 8][kb + kk];
                float4 a2 = *(const float4*)&A[mg2 + 16][kb + kk];
                float4 a3 = {0.f, 0.f, 0.f, 0.f};
                if (mg2 == 0) a3 = *(const float4*)&A[24][kb + kk];
#pragma unroll
                for (int j = 0; j < 2; j++) {
                    float4 w4 = *(const float4*)&sWc[nh2 + 64 * j][kk];
                    acc[j][0] += w4.x * a0.x + w4.y * a0.y + w4.z * a0.z + w4.w * a0.w;
                    acc[j][1] += w4.x * a1.x + w4.y * a1.y + w4.z * a1.z + w4.w * a1.w;
                    acc[j][2] += w4.x * a2.x + w4.y * a2.y + w4.z * a2.z + w4.w * a2.w;
                    acc[j][3] += w4.x * a3.x + w4.y * a3.y + w4.z * a3.z + w4.w * a3.w;
                }
            }
            __syncthreads();
        }
#pragma unroll
        for (int j = 0; j < 2; j++) {
            int n = nh2 + 64 * j;
            float bv = bias[n];
            gdst[(mg2) * DD + n]      = acc[j][0] + bv;
            gdst[(mg2 + 8) * DD + n]  = acc[j][1] + bv;
            gdst[(mg2 + 16) * DD + n] = acc[j][2] + bv;
            if (mg2 == 0) gdst[24 * DD + n] = acc[j][3] + bv;
        }
    };

    // ================= embed: own 25 rows ==================================
    for (int i = t; i < 800; i += NTHR) {
        int l = i >> 5, c = (i & 31) << 2;
        int bl = b * LL + l;
        int u = user[bl], p = poi[bl], cc = cat[bl], td = tod[bl], dw = dow[bl];
        float4 a0 = *(const float4*)(ue + u * DD + c);
        float4 a1 = *(const float4*)(pe + p * DD + c);
        float4 a2 = *(const float4*)(te + td * DD + c);
        float4 a3 = *(const float4*)(de + dw * DD + c);
        float4 x;
        x.x = a0.x + a1.x + a2.x + a3.x; x.y = a0.y + a1.y + a2.y + a3.y;
        x.z = a0.z + a1.z + a2.z + a3.z; x.w = a0.w + a1.w + a2.w + a3.w;
        *(float4*)(O0 + bl * DD + c) = x;
        float4 b0 = *(const float4*)(uec + u * DD + c);
        float4 b1 = *(const float4*)(ce + cc * DD + c);
        float4 b2 = *(const float4*)(tec + td * DD + c);
        float4 b3 = *(const float4*)(dec + dw * DD + c);
        float4 xc;
        xc.x = b0.x + b1.x + b2.x + b3.x; xc.y = b0.y + b1.y + b2.y + b3.y;
        xc.z = b0.z + b1.z + b2.z + b3.z; xc.w = b0.w + b1.w + b2.w + b3.w;
        *(float4*)(C0 + bl * DD + c) = xc;
    }
    __syncthreads();

    // ================= 8 autocorrelation-attention calls ===================
    float* bufs[4] = {O0, C0, O1, C1};
    const int qsel[8] = {0, 1, 2, 3, 0, 1, 2, 3};
    const int ksel[8] = {0, 1, 3, 0, 0, 1, 3, 0};
    const int dsel[8] = {2, 3, 0, 1, 2, 3, 0, 1};

    float* Qb = Qg + b * LL * DD;
    float* Kb = Kg + b * LL * DD;
    float* Vb = Vg + b * LL * DD;

#pragma unroll 1
    for (int ci = 0; ci < 8; ++ci) {
        const float* qx  = bufs[qsel[ci]] + b * LL * DD;
        const float* kx  = bufs[ksel[ci]] + b * LL * DD;   // kx == vx
        float*       dst = bufs[dsel[ci]] + b * LL * DD;
        const float* Wb  = W  + (size_t)ci * 4 * DD * DD;
        const float* Bb  = Bv + (size_t)ci * 4 * DD;

        // ---- stage src rows
        for (int i = t; i < 800; i += NTHR) {
            int l = i >> 5, c = (i & 31) << 2;
            *(float4*)&sA[l][c] = *(const float4*)(qx + l * DD + c);
            *(float4*)&sB[l][c] = *(const float4*)(kx + l * DD + c);
        }
        __syncthreads();

        // ---- proj q/k/v (Q from sA; K,V from sB)
        gemm(sA, Wb,               Bb,          Qb);
        gemm(sB, Wb + 1 * DD * DD, Bb + DD,     Kb);
        gemm(sB, Wb + 2 * DD * DD, Bb + 2 * DD, Vb);

        // ---- re-stage Q,K (own writes, L1/L2-hot) for corr
        __syncthreads();
        for (int i = t; i < 800; i += NTHR) {
            int l = i >> 5, c = (i & 31) << 2;
            *(float4*)&sA[l][c] = *(const float4*)(Qb + l * DD + c);
            *(float4*)&sB[l][c] = *(const float4*)(Kb + l * DD + c);
        }
        __syncthreads();

        // ---- corr: mv[tau] = (1/128) sum_s Q[(s+tau)%25,:] . K[s,:]
        int lid = t & 63, wid = t >> 6;
        for (int tau = 0; tau < LL; tau++) {
            float s = 0.f;
            for (int e = t; e < 800; e += NTHR) {
                int srow = e >> 5, dc = (e & 31) << 2;
                int qrow = srow + tau; if (qrow >= LL) qrow -= LL;
                float4 a = *(const float4*)&sA[qrow][dc];
                float4 g = *(const float4*)&sB[srow][dc];
                s += a.x * g.x + a.y * g.y + a.z * g.z + a.w * g.w;
            }
            for (int off = 32; off > 0; off >>= 1) s += __shfl_down(s, off);
            if (lid == 0) crb[tau][wid] = s;
        }
        __syncthreads();
        if (t < LL) {
            float v = (crb[t][0] + crb[t][1] + crb[t][2] + crb[t][3] +
                       crb[t][4] + crb[t][5] + crb[t][6] + crb[t][7]) * (1.0f / 128.0f);
            smv[t] = v;
            __hip_atomic_store(&MVu[ci * BL + b * LL + t], __float_as_uint(v),
                               __ATOMIC_RELAXED, __HIP_MEMORY_SCOPE_AGENT);
        }

        // ---- the one cross-block sync per call
        mvsync(cnt, ci, bx);

        // ---- batch-mean over b (coherent loads), redundant per block
        if (t < 200) {
            int g = t / LL, tau = t - g * LL;
            float s = 0.f;
#pragma unroll
            for (int k2 = 0; k2 < 8; k2++) {
                int b2 = g * 8 + k2;
                s += __uint_as_float(__hip_atomic_load(&MVu[ci * BL + b2 * LL + tau],
                                                       __ATOMIC_RELAXED,
                                                       __HIP_MEMORY_SCOPE_AGENT));
            }
            pbm[g][tau] = s;
        }
        __syncthreads();
        if (t < LL) {
            float s = 0.f;
#pragma unroll
            for (int g = 0; g < 8; g++) s += pbm[g][t];
            sbm[t] = s;
        }
        __syncthreads();
        if (t == 0) {
            float loc[LL];
            for (int i = 0; i < LL; i++) loc[i] = sbm[i];
            for (int j = 0; j < 3; j++) {
                int bi = 0; float bvv = loc[0];
                for (int i = 1; i < LL; i++) if (loc[i] > bvv) { bvv = loc[i]; bi = i; }
                sidx[j] = bi; loc[bi] = -1e30f;
            }
            float w0 = smv[sidx[0]], w1 = smv[sidx[1]], w2 = smv[sidx[2]];
            float m = fmaxf(w0, fmaxf(w1, w2));
            float e0 = expf(w0 - m), e1 = expf(w1 - m), e2 = expf(w2 - m);
            float inv = 1.0f / (e0 + e1 + e2);
            sw3[0] = e0 * inv; sw3[1] = e1 * inv; sw3[2] = e2 * inv;
        }
        __syncthreads();

        // ---- agg into sA (V rows are own writes, L2-hot)
        {
            int i0 = sidx[0], i1 = sidx[1], i2x = sidx[2];
            float w0 = sw3[0], w1 = sw3[1], w2 = sw3[2];
            for (int i = t; i < 800; i += NTHR) {
                int l = i >> 5, c = (i & 31) << 2;
                int l0 = l + i0;  if (l0 >= LL) l0 -= LL;
                int l1 = l + i1;  if (l1 >= LL) l1 -= LL;
                int l2 = l + i2x; if (l2 >= LL) l2 -= LL;
                float4 v0 = *(const float4*)(Vb + l0 * DD + c);
                float4 v1 = *(const float4*)(Vb + l1 * DD + c);
                float4 v2 = *(const float4*)(Vb + l2 * DD + c);
                float4 a;
                a.x = w0 * v0.x + w1 * v1.x + w2 * v2.x;
                a.y = w0 * v0.y + w1 * v1.y + w2 * v2.y;
                a.z = w0 * v0.z + w1 * v1.z + w2 * v2.z;
                a.w = w0 * v0.w + w1 * v1.w + w2 * v2.w;
                *(float4*)&sA[l][c] = a;
            }
            __syncthreads();
        }

        // ---- out-proj: dst = agg @ W3^T + b3
        gemm(sA, Wb + 3 * DD * DD, Bb + 3 * DD, dst);
        __syncthreads();
    }

    // ================= precat: own b =======================================
    {
        if (t < LL) svw[t] = vw[t];
        __syncthreads();
        if (t < DD) {
            float s = 0.f;
            for (int l = 0; l < LL; l++) s += svw[l] * C0[(b * LL + l) * DD + t];
            yv[t] = s;
        }
        __syncthreads();
        float vb = vbp[0];
        for (int c = t; c < CAT_N; c += NTHR) {
            float s = 0.f;
            for (int d = 0; d < DD; d += 4) {
                float4 ce4 = *(const float4*)(ce + c * DD + d);
                s += ce4.x * yv[d] + ce4.y * yv[d + 1] + ce4.z * yv[d + 2] + ce4.w * yv[d + 3];
            }
            out_cat[b * CAT_N + c] = s + vb;
        }
    }
}

// ---------------------------------------------------------------------------
// pre_poi[b,p] = vb + sum_l vw[l] * exp(-D[poi[b,l],p]/(gmax-gmin))
//                                 * (poi_emb[p] . out[b,l,:])
// sS overlaid on sPc (sS only written after the final kb barrier, when all
// sPc reads are done). LDS 61KB -> 48.5KB => 3 blocks/CU (was 1) => 3
// waves/SIMD during the latency-bound phases.
// ---------------------------------------------------------------------------
__global__ __launch_bounds__(256, 3) void prepoi_kernel(
    const float* __restrict__ outp, const float* __restrict__ poi_emb,
    const int* __restrict__ poi_idx, const float* __restrict__ Dm,
    const float* __restrict__ mmf, const float* __restrict__ vw,
    const float* __restrict__ vbp, float* __restrict__ dstp)
{
    int b = blockIdx.y;
    int pbase = blockIdx.x << 7;
    __shared__ float sO[LL][132];
    __shared__ __align__(16) char ovl[128 * 68 * 4];                 // sPc / sS overlay
    float (*sPc)[68]  = reinterpret_cast<float(*)[68]>(ovl);
    float (*sS)[132]  = reinterpret_cast<float(*)[132]>(ovl);
    __shared__ float svw[LL];
    __shared__ int srow[LL];
    __shared__ float red[128];
    int t = threadIdx.x;

    for (int i = t; i < 800; i += 256) {
        int l = i >> 5, c = (i & 31) << 2;
        *(float4*)&sO[l][c] = *(const float4*)(outp + (b * LL + l) * DD + c);
    }
    if (t < LL) { svw[t] = vw[t]; srow[t] = poi_idx[b * LL + t]; }
    __syncthreads();

    int nh = t & 31, mg = t >> 5;
    float acc[4][4] = {};
    for (int kb = 0; kb < 128; kb += 64) {
        for (int i = t; i < 128 * 16; i += 256) {
            int p = i >> 4, c = (i & 15) << 2;
            float4 val = {0.f, 0.f, 0.f, 0.f};
            if (pbase + p < POI_N) val = *(const float4*)(poi_emb + (pbase + p) * DD + kb + c);
            *(float4*)&sPc[p][c] = val;
        }
        __syncthreads();
#pragma unroll 4
        for (int kk = 0; kk < 64; kk += 4) {
            float4 a0 = *(const float4*)&sO[mg][kb + kk];
            float4 a1 = *(const float4*)&sO[mg + 8][kb + kk];
            float4 a2 = *(const float4*)&sO[mg + 16][kb + kk];
            float4 a3 = {0.f, 0.f, 0.f, 0.f};
            if (mg == 0) a3 = *(const float4*)&sO[24][kb + kk];
#pragma unroll
            for (int j = 0; j < 4; j++) {
                float4 p4 = *(const float4*)&sPc[nh + 32 * j][kk];
                acc[j][0] += p4.x * a0.x + p4.y * a0.y + p4.z * a0.z + p4.w * a0.w;
                acc[j][1] += p4.x * a1.x + p4.y * a1.y + p4.z * a1.z + p4.w * a1.w;
                acc[j][2] += p4.x * a2.x + p4.y * a2.y + p4.z * a2.z + p4.w * a2.w;
                acc[j][3] += p4.x * a3.x + p4.y * a3.y + p4.z * a3.z + p4.w * a3.w;
            }
        }
        __syncthreads();   // after final kb iter: all sPc reads done -> overlay safe
    }
#pragma unroll
    for (int j = 0; j < 4; j++) {
        int pl = nh + 32 * j;
        sS[mg][pl]      = acc[j][0];
        sS[mg + 8][pl]  = acc[j][1];
        sS[mg + 16][pl] = acc[j][2];
        if (mg == 0) sS[24][pl] = acc[j][3];
    }
    __syncthreads();

    float gmax = mmf[0];
    float gmin = mmf[1];
    float ninv = -1.0f / (gmax - gmin);
    int pp = t & 127, half = t >> 7;
    int p = pbase + pp;
    float s = 0.f;
    if (p < POI_N) {
        int l0 = half ? 13 : 0, l1 = half ? 25 : 13;
        for (int l = l0; l < l1; l++) {
            float dv = Dm[(size_t)srow[l] * POI_N + p];
            s += svw[l] * expf(dv * ninv) * sS[l][pp];
        }
    }
    if (half) red[pp] = s;
    __syncthreads();
    if (!half && p < POI_N)
        dstp[(size_t)b * POI_N + p] = s + red[pp] + vbp[0];
}

// ---------------------------------------------------------------------------
extern "C" void kernel_launch(void* const* d_in, const int* in_sizes, int n_in,
                              void* d_out, int out_size, void* d_ws, size_t ws_size,
                              hipStream_t stream)
{
    const int*   user = (const int*)d_in[0];
    const int*   poi  = (const int*)d_in[1];
    const int*   cat  = (const int*)d_in[2];
    const int*   tod  = (const int*)d_in[5];
    const int*   dow  = (const int*)d_in[6];
    const float* ue   = (const float*)d_in[8];
    const float* pe   = (const float*)d_in[9];
    const float* ce   = (const float*)d_in[10];
    const float* te   = (const float*)d_in[11];
    const float* de   = (const float*)d_in[12];
    const float* uec  = (const float*)d_in[13];
    const float* tec  = (const float*)d_in[14];
    const float* dec  = (const float*)d_in[15];
    const float* W    = (const float*)d_in[16];
    const float* Bv   = (const float*)d_in[17];
    const float* vw   = (const float*)d_in[18];
    const float* vb   = (const float*)d_in[19];
    const float* Dm   = (const float*)d_in[20];

    float* ws = (float*)d_ws;
    float* O0 = ws;
    float* C0 = ws + 204800;
    float* O1 = ws + 409600;
    float* C1 = ws + 614400;
    float* Qg = ws + 819200;
    float* Kg = ws + 1024000;
    float* Vg = ws + 1228800;
    unsigned* MVu = (unsigned*)(ws + 1433600);     // 8 calls x 1600 mv mailbox
    float* mxA = ws + 1446400;                     // 1600
    float* mnA = ws + 1448000;                     // 1600
    unsigned* CNT = (unsigned*)(ws + 1449600);     // 8 calls x 8 shards x 32
    float* MMF = ws + 1449600 + 2048;              // gmax, gmin

    float* out_poi = (float*)d_out;
    float* out_cat = out_poi + BB * POI_N;

    // zero the sync counters only
    hipMemsetAsync(CNT, 0, 8 * NSH * 32 * sizeof(unsigned), stream);

    minmax1_kernel<<<BL, 256, 0, stream>>>(poi, Dm, mxA, mnA);
    minmax2_kernel<<<1, 256, 0, stream>>>(mxA, mnA, MMF);

    persist_kernel<<<NBLK, NTHR, 0, stream>>>(
        user, poi, cat, tod, dow, ue, pe, ce, te, de, uec, tec, dec,
        W, Bv, vw, vb, O0, C0, O1, C1, Qg, Kg, Vg, MVu, CNT, out_cat);

    prepoi_kernel<<<dim3(79, BB), 256, 0, stream>>>(O0, pe, poi, Dm, MMF, vw, vb, out_poi);
}